// Round 2
// baseline (622.469 us; speedup 1.0000x reference)
//
#include <hip/hip_runtime.h>

#define BB 8
#define CC_ALL 128
#define HH 160
#define WW 160
#define PAD 4
#define RANGE 9
#define ND 80           // 81 - center
#define NG 3            // disparity-row groups (di 0-2, 3-5, 6-8)
#define DR 3            // disparity rows per group
#define TW 32           // tile width (px)
#define TH 16           // tile height (px)
#define PXT 2           // px per thread along w
#define NTX (TW / PXT)  // 16
#define CCHUNK 8        // channels staged per LDS chunk
#define HALO_W (TW + 2 * PAD)  // 40
#define HALO_H (TH + 2)        // 18 rows cover di-group's 3 offsets
#define PLANE (HH * WW)        // 25600
#define NACC (DR * RANGE * PXT)  // 54

__global__ __launch_bounds__(256, 4)
void cost_volume_kernel(const float* __restrict__ f1,
                        const float* __restrict__ f2,
                        float* __restrict__ out) {
    __shared__ __align__(16) float s2[CCHUNK][HALO_H][HALO_W];

    const int tile_x = blockIdx.x;          // 0..4
    const int tile_y = blockIdx.y;          // 0..9
    const int bz     = blockIdx.z;          // 0..23
    const int b = bz / NG;
    const int g = bz - b * NG;              // disparity group 0..2
    const int w0 = tile_x * TW;
    const int h0 = tile_y * TH;
    const int tid = threadIdx.x;
    const int tx = tid & (NTX - 1);         // 0..15
    const int ty = tid >> 4;                // 0..15
    const int w = w0 + tx * PXT;            // even
    const int h = h0 + ty;

    // group g covers di = 3g..3g+2, i.e. f2 rows [h0 + 3g - 4, h0 + TH-1 + 3g - 2]
    const int row_start = h0 + 3 * g - PAD;

    float acc[NACC];
#pragma unroll
    for (int i = 0; i < NACC; i++) acc[i] = 0.f;

    const float* f1base = f1 + (size_t)b * CC_ALL * PLANE + (size_t)h * WW + w;
    const float* f2base = f2 + (size_t)b * CC_ALL * PLANE;

    for (int c0 = 0; c0 < CC_ALL; c0 += CCHUNK) {
        // ---- stage CCHUNK channels of this group's feat2 halo into LDS ----
        // elems: 8*18*40 = 5760
        for (int idx = tid; idx < CCHUNK * HALO_H * HALO_W; idx += 256) {
            const int cw = idx % HALO_W;
            const int t  = idx / HALO_W;
            const int rr = t % HALO_H;
            const int cc = t / HALO_H;
            const int gw = w0 - PAD + cw;
            const int gh = row_start + rr;
            float v = 0.f;
            if ((unsigned)gw < WW && (unsigned)gh < HH)
                v = f2base[(size_t)(c0 + cc) * PLANE + (size_t)gh * WW + gw];
            s2[cc][rr][cw] = v;
        }
        __syncthreads();

#pragma unroll
        for (int cc = 0; cc < CCHUNK; cc++) {
            const float2 f1v = *(const float2*)(f1base + (size_t)(c0 + cc) * PLANE);
#pragma unroll
            for (int r = 0; r < DR; r++) {
                // f2 row for di = 3g + r at output row h: gh = h + 3g + r - 4
                //   LDS row = gh - row_start = ty + r
                const float* rowp = &s2[cc][ty + r][tx * PXT];
                float win[10];  // w-4 .. w+5
#pragma unroll
                for (int k = 0; k < 5; k++) {
                    const float2 t2 = *(const float2*)(rowp + 2 * k);
                    win[2 * k]     = t2.x;
                    win[2 * k + 1] = t2.y;
                }
#pragma unroll
                for (int dj = 0; dj < RANGE; dj++) {
                    acc[(r * RANGE + dj) * 2 + 0] += f1v.x * win[dj];
                    acc[(r * RANGE + dj) * 2 + 1] += f1v.y * win[dj + 1];
                }
            }
        }
        __syncthreads();
    }

    // ---- epilogue: mean (x 1/128) and store; skip center (lin==40) ----
    float* outb = out + (size_t)b * ND * PLANE + (size_t)h * WW + w;
#pragma unroll
    for (int r = 0; r < DR; r++) {
#pragma unroll
        for (int dj = 0; dj < RANGE; dj++) {
            const int lin = (3 * g + r) * RANGE + dj;
            if (lin == 40) continue;          // center shift excluded
            const int d = (lin < 40) ? lin : (lin - 1);
            float2 o;
            o.x = acc[(r * RANGE + dj) * 2 + 0] * (1.f / 128.f);
            o.y = acc[(r * RANGE + dj) * 2 + 1] * (1.f / 128.f);
            *(float2*)(outb + (size_t)d * PLANE) = o;
        }
    }
}

extern "C" void kernel_launch(void* const* d_in, const int* in_sizes, int n_in,
                              void* d_out, int out_size, void* d_ws, size_t ws_size,
                              hipStream_t stream) {
    const float* feat1 = (const float*)d_in[0];
    const float* feat2 = (const float*)d_in[1];
    float* out = (float*)d_out;

    dim3 grid(WW / TW, HH / TH, BB * NG);   // 5 x 10 x 24 = 1200 blocks
    dim3 block(256);
    cost_volume_kernel<<<grid, block, 0, stream>>>(feat1, feat2, out);
}

// Round 3
// 431.334 us; speedup vs baseline: 1.4431x; 1.4431x over previous
//
#include <hip/hip_runtime.h>

#define BB 8
#define CC_ALL 128
#define HH 160
#define WW 160
#define PAD 4
#define RANGE 9
#define ND 80
#define NG 3                  // di groups (rows 0-2, 3-5, 6-8)
#define DR 3                  // di rows per group
#define TH 8                  // tile height (full width tile: 160 x 8)
#define NTX 40                // lanes per image row
#define PXT 4                 // px per thread along w (aligned float4)
#define NTHREADS 320          // 40 x 8 = 5 waves
#define CCHUNK 8
#define NROWS (TH + DR - 1)   // 10 f2 rows cover this group's 3 di offsets
#define ROWF (WW + 2 * PAD)   // 168 floats per LDS row (4 pad each side)
#define PLANE (HH * WW)       // 25600
#define NSLOT (CCHUNK * NROWS * (WW / 4) / NTHREADS)  // 10 float4 slots/thread
#define NACC (DR * RANGE * PXT)  // 108

__global__ __launch_bounds__(NTHREADS, 1)
void cost_volume_kernel(const float* __restrict__ f1,
                        const float* __restrict__ f2,
                        float* __restrict__ out) {
    __shared__ __align__(16) float s2[CCHUNK][NROWS][ROWF];

    const int tile_y = blockIdx.x;              // 0..19
    const int bz     = blockIdx.y;              // 0..23
    const int b = bz / NG;
    const int g = bz - b * NG;                  // di group
    const int h0 = tile_y * TH;
    const int tid = threadIdx.x;
    const int tx = tid % NTX;                   // 0..39
    const int ty = tid / NTX;                   // 0..7
    const int w = tx * PXT;                     // multiple of 4
    const int h = h0 + ty;
    const int row_start = h0 + DR * g - PAD;    // image row of LDS row 0

    // ---- zero LDS once: pad columns + OOB rows stay zero forever ----
    {
        float* p = &s2[0][0][0];
        for (int i = tid; i < CCHUNK * NROWS * ROWF; i += NTHREADS) p[i] = 0.f;
    }

    // ---- precompute staging slots (channel-invariant) ----
    // slot s -> (cc, row, quad): writes f2[c0+cc][row_start+row][quad*4 .. +3]
    int glb_off[NSLOT];
    int lds_off[NSLOT];
    unsigned vmask = 0;
    {
#pragma unroll
        for (int k = 0; k < NSLOT; k++) {
            const int s = tid + k * NTHREADS;
            const int quad = s % (WW / 4);
            const int t = s / (WW / 4);
            const int row = t % NROWS;
            const int cc = t / NROWS;
            const int gh = row_start + row;
            glb_off[k] = cc * PLANE + gh * WW + quad * 4;
            lds_off[k] = (cc * NROWS + row) * ROWF + PAD + quad * 4;
            if ((unsigned)gh < HH) vmask |= (1u << k);
        }
    }

    float acc[NACC];
#pragma unroll
    for (int i = 0; i < NACC; i++) acc[i] = 0.f;

    const float* f1p = f1 + (size_t)b * CC_ALL * PLANE + (size_t)h * WW + w;
    const float* f2b = f2 + (size_t)b * CC_ALL * PLANE;
    float* s2f = &s2[0][0][0];

    for (int c0 = 0; c0 < CC_ALL; c0 += CCHUNK) {
        // ---- stage: 10 aligned float4 global->LDS per thread, no div/mod ----
#pragma unroll
        for (int k = 0; k < NSLOT; k++) {
            if (vmask & (1u << k)) {
                const float4 v = *(const float4*)(f2b + (size_t)c0 * PLANE + glb_off[k]);
                *(float4*)(s2f + lds_off[k]) = v;
            }
        }
        __syncthreads();

        // ---- compute ----
#pragma unroll
        for (int cc = 0; cc < CCHUNK; cc++) {
            const float4 a = *(const float4*)(f1p + (size_t)(c0 + cc) * PLANE);
            const float av[PXT] = {a.x, a.y, a.z, a.w};
#pragma unroll
            for (int r = 0; r < DR; r++) {
                // LDS cols 4tx .. 4tx+11  <->  image w-4 .. w+7 : 3 aligned b128
                const float* rp = &s2[cc][ty + r][w];
                float win[12];
                *(float4*)&win[0] = *(const float4*)(rp);
                *(float4*)&win[4] = *(const float4*)(rp + 4);
                *(float4*)&win[8] = *(const float4*)(rp + 8);
#pragma unroll
                for (int dj = 0; dj < RANGE; dj++) {
#pragma unroll
                    for (int p = 0; p < PXT; p++) {
                        acc[(r * RANGE + dj) * PXT + p] += av[p] * win[dj + p];
                    }
                }
            }
        }
        __syncthreads();
    }

    // ---- epilogue: mean and store (skip center lin==40) ----
    float* ob = out + (size_t)b * ND * PLANE + (size_t)h * WW + w;
#pragma unroll
    for (int r = 0; r < DR; r++) {
#pragma unroll
        for (int dj = 0; dj < RANGE; dj++) {
            const int lin = (DR * g + r) * RANGE + dj;
            if (lin == 40) continue;            // block-uniform branch
            const int d = lin - (lin > 40 ? 1 : 0);
            float4 o;
            o.x = acc[(r * RANGE + dj) * PXT + 0] * (1.f / 128.f);
            o.y = acc[(r * RANGE + dj) * PXT + 1] * (1.f / 128.f);
            o.z = acc[(r * RANGE + dj) * PXT + 2] * (1.f / 128.f);
            o.w = acc[(r * RANGE + dj) * PXT + 3] * (1.f / 128.f);
            *(float4*)(ob + (size_t)d * PLANE) = o;
        }
    }
}

extern "C" void kernel_launch(void* const* d_in, const int* in_sizes, int n_in,
                              void* d_out, int out_size, void* d_ws, size_t ws_size,
                              hipStream_t stream) {
    const float* feat1 = (const float*)d_in[0];
    const float* feat2 = (const float*)d_in[1];
    float* out = (float*)d_out;

    dim3 grid(HH / TH, BB * NG);   // 20 x 24 = 480 blocks
    dim3 block(NTHREADS);
    cost_volume_kernel<<<grid, block, 0, stream>>>(feat1, feat2, out);
}